// Round 10
// baseline (507.956 us; speedup 1.0000x reference)
//
#include <hip/hip_runtime.h>

// B=1024 groups, T=256 steps, S=16 states, M=4 measurements
#define NT 256
#define NSTEP 255

__device__ __forceinline__ float dot4(float4 a, float4 b) {
    return a.x*b.x + a.y*b.y + a.z*b.z + a.w*b.w;
}
__device__ __forceinline__ float4 shfl4(float4 x, int src) {
    return make_float4(__shfl(x.x, src), __shfl(x.y, src),
                       __shfl(x.z, src), __shfl(x.w, src));
}

// -----------------------------------------------------------------------------
// R10: 256 blocks x 64 threads (1 wave/CU), each block redundantly runs the
// shared Riccati (Joseph form) fused with the filter for its own 4 batches
// (R9 structure), restructured from 5 LDS round-trips/step to 3:
//   s1: read P row j -> tf[4] = (F P)[q+4r][j], ph[4] = HP[:][j] (LOCAL, new);
//       write HP[q][j] (one scalar).
//   s2: read HP row bm -> V[bi][bm] and OWN S row bm locally; gather other
//       S rows (12 bpermute) + V row bi (4) -> cofactors/det/B lane-local;
//       scatter B rows to (q,j) partition (16+4 bpermute). NO LDS.
//   s3: A[i][j] = F - B*H, AP[i][j] = tf - B.ph (ph local!) -> write A,AP.
//   s4: read A row j + AP rows -> P' = AP A^T + B(R B_j) + Q -> write P;
//       fused filter step (z in regs, 16-shfl broadcast, proven R9 code).
// Conv-freeze removed: measured (R5/R8/R9) it never fires before t~250 for
// this F (rho(A_cl)^2 ~ 0.96) — pure overhead.
// -----------------------------------------------------------------------------
__global__ __launch_bounds__(64) void kf_block_kernel(
    const float* __restrict__ obs, const float* __restrict__ Fg,
    const float* __restrict__ Hg,  const float* __restrict__ Qg,
    const float* __restrict__ Rg,  const float* __restrict__ x0g,
    const float* __restrict__ sdg, float* __restrict__ out)
{
    __shared__ float4 sF4[80];     // F, row stride 20 (init z0 only)
    __shared__ float4 sP4[80];     // P, stride 20
    __shared__ float4 sA4[80];     // A, stride 20
    __shared__ float4 sAP4[80];    // AP, stride 20
    __shared__ float4 sHP4[16];    // HP rows, stride 16 (4 rows x 4 float4)
    __shared__ float  sZ[16];      // z0
    __shared__ float4 sObs4[1024]; // [g][t] observations, 16 KB
    __shared__ float4 sOut4[1024]; // [g][t] outputs, 16 KB

    float* sF  = (float*)sF4;
    float* sP  = (float*)sP4;
    float* sA  = (float*)sA4;
    float* sAP = (float*)sAP4;
    float* sHP = (float*)sHP4;
    float* sOut = (float*)sOut4;

    const int tid = threadIdx.x;
    const int q  = tid >> 4;      // row quad 0..3 (= filter batch group g)
    const int j  = tid & 15;      // column 0..15  (= filter state index i)
    const int bi = tid >> 2;      // B row 0..15
    const int bm = tid & 3;       // B col / S row 0..3
    const int gbase = tid & 48;   // first lane of this 16-lane group
    const int qbase = tid & ~3;   // first lane of this 4-lane quad

    const float4* Fg4 = (const float4*)Fg;
    const float4* Hg4 = (const float4*)Hg;
    const float4* Rg4 = (const float4*)Rg;
    const float4* obs4g = (const float4*)obs;

    // ---- stage F (init) and obs into LDS ----
    for (int u = tid; u < 256; u += 64) sF[(u >> 4) * 20 + (u & 15)] = Fg[u];
    for (int u = tid; u < 1024; u += 64)
        sObs4[u] = obs4g[(blockIdx.x * 4 + (u >> 8)) * NT + (u & 255)];

    // ---- per-lane register preloads ----
    float4 zF[4][4], zFbi[4], zFj[4], zHall[4][4], zHrow4[4];
#pragma unroll
    for (int r = 0; r < 4; ++r)
#pragma unroll
        for (int f = 0; f < 4; ++f) zF[r][f] = Fg4[(q + 4*r)*4 + f];
#pragma unroll
    for (int m = 0; m < 4; ++m)
#pragma unroll
        for (int f = 0; f < 4; ++f) zHall[m][f] = Hg4[m*4 + f];
#pragma unroll
    for (int f = 0; f < 4; ++f) {
        zFbi[f]   = Fg4[bi*4 + f];        // F row bi    (V stage)
        zFj[f]    = Fg4[j*4 + f];         // F row j     (init only)
        zHrow4[f] = Hg4[(j & 3)*4 + f];   // H row (j&3) (filter output)
    }
    float hr[16] = {zHrow4[0].x,zHrow4[0].y,zHrow4[0].z,zHrow4[0].w,
                    zHrow4[1].x,zHrow4[1].y,zHrow4[1].z,zHrow4[1].w,
                    zHrow4[2].x,zHrow4[2].y,zHrow4[2].z,zHrow4[2].w,
                    zHrow4[3].x,zHrow4[3].y,zHrow4[3].z,zHrow4[3].w};
    float zQ[4];
#pragma unroll
    for (int r = 0; r < 4; ++r) zQ[r] = Qg[(q + 4*r)*16 + j];
    float4 zR4[4];
#pragma unroll
    for (int m = 0; m < 4; ++m) zR4[m] = Rg4[m];
    float4 zRbm = Rg4[bm];                                                 // R row bm
    float4 zHcjv = make_float4(Hg[j], Hg[16 + j], Hg[32 + j], Hg[48 + j]); // H col j
    float4 zFijv = make_float4(Fg[q*16 + j],      Fg[(q+4)*16 + j],
                               Fg[(q+8)*16 + j],  Fg[(q+12)*16 + j]);      // F[q+4r][j]
    float4 zSd2[4];
#pragma unroll
    for (int f = 0; f < 4; ++f) {
        float4 s = ((const float4*)sdg)[f];
        zSd2[f] = make_float4(s.x*s.x, s.y*s.y, s.z*s.z, s.w*s.w);
    }
    __syncthreads();   // sF, sObs ready

    // ---- P0 = F diag(sd^2) F^T + Q ----
#pragma unroll
    for (int r = 0; r < 4; ++r) {
        float acc = zQ[r];
#pragma unroll
        for (int f = 0; f < 4; ++f) {
            float4 a = zF[r][f], b = zFj[f], s = zSd2[f];
            acc += a.x*s.x*b.x + a.y*s.y*b.y + a.z*s.z*b.z + a.w*s.w*b.w;
        }
        sP[(q + 4*r)*20 + j] = acc;
    }
    // ---- z0 = F x0 ----
    if (tid < 16) {
        float acc = 0.f;
#pragma unroll
        for (int f = 0; f < 4; ++f) {
            float4 fr = ((float4*)(sF + tid*20))[f];
            float4 xv = ((const float4*)x0g)[f];
            acc += dot4(fr, xv);
        }
        sZ[tid] = acc;
    }
    __syncthreads();
    float zr = sZ[j];    // lane (g=q, i=j) holds z_i for batch blockIdx*4+q

    for (int t = 0; t < NSTEP; ++t) {
        // ---- s1: read P row j; tf = (F P)[q+4r][j]; ph[m] = HP[m][j] ----
        float4 zP[4];
#pragma unroll
        for (int f = 0; f < 4; ++f) zP[f] = sP4[j*5 + f];
        float tf[4], ph[4];
#pragma unroll
        for (int r = 0; r < 4; ++r) {
            float acc = 0.f;
#pragma unroll
            for (int f = 0; f < 4; ++f) acc += dot4(zF[r][f], zP[f]);
            tf[r] = acc;
        }
#pragma unroll
        for (int m = 0; m < 4; ++m) {
            float acc = 0.f;
#pragma unroll
            for (int f = 0; f < 4; ++f) acc += dot4(zHall[m][f], zP[f]);
            ph[m] = acc;
        }
        sHP[q*16 + j] = ph[q];     // group q writes HP row q
        __syncthreads();

        // ---- s2 (no LDS writes): V, S, B all via shfl ----
        float4 hpr[4];             // HP row bm (broadcast read, conflict-free)
#pragma unroll
        for (int f = 0; f < 4; ++f) hpr[f] = sHP4[bm*4 + f];
        float v = 0.f;             // V[bi][bm] = F_bi . HP_bm
#pragma unroll
        for (int f = 0; f < 4; ++f) v += dot4(zFbi[f], hpr[f]);
        float4 srow;               // own S row bm: S[bm][n] = HP_bm . H_n + R[bm][n]
        {
            float sn[4];
#pragma unroll
            for (int n = 0; n < 4; ++n) {
                float acc = 0.f;
#pragma unroll
                for (int f = 0; f < 4; ++f) acc += dot4(hpr[f], zHall[n][f]);
                sn[n] = acc;
            }
            srow = make_float4(sn[0] + zRbm.x, sn[1] + zRbm.y,
                               sn[2] + zRbm.z, sn[3] + zRbm.w);
        }
        // gather the 3 other S rows with computed source lanes (no reg indexing)
        int ra = (bm == 0) ? 1 : 0;
        int rb = (bm <= 1) ? 2 : 1;
        int rc = (bm <= 2) ? 3 : 2;
        float4 a = shfl4(srow, qbase | ra);
        float4 b = shfl4(srow, qbase | rb);
        float4 c = shfl4(srow, qbase | rc);
        float4 sm = srow;          // own row bm
        float M0 = a.y*(b.z*c.w - b.w*c.z) - a.z*(b.y*c.w - b.w*c.y) + a.w*(b.y*c.z - b.z*c.y);
        float M1 = a.x*(b.z*c.w - b.w*c.z) - a.z*(b.x*c.w - b.w*c.x) + a.w*(b.x*c.z - b.z*c.x);
        float M2 = a.x*(b.y*c.w - b.w*c.y) - a.y*(b.x*c.w - b.w*c.x) + a.w*(b.x*c.y - b.y*c.x);
        float M3 = a.x*(b.y*c.z - b.z*c.y) - a.y*(b.x*c.z - b.z*c.x) + a.z*(b.x*c.y - b.y*c.x);
        float sg = (bm & 1) ? -1.f : 1.f;
        float c0 = sg*M0, c1 = -sg*M1, c2 = sg*M2, c3 = -sg*M3;
        float det = sm.x*c0 + sm.y*c1 + sm.z*c2 + sm.w*c3;
        float4 vv = make_float4(__shfl(v, qbase | 0), __shfl(v, qbase | 1),
                                __shfl(v, qbase | 2), __shfl(v, qbase | 3)); // V row bi
        float bscal = (vv.x*c0 + vv.y*c1 + vv.z*c2 + vv.w*c3) / det;        // B[bi][bm]
        // scatter B to the (q,j) partition: rows q+4r and row j
        float4 bq[4];
#pragma unroll
        for (int r = 0; r < 4; ++r) {
            int lb = (q + 4*r) << 2;
            bq[r] = make_float4(__shfl(bscal, lb | 0), __shfl(bscal, lb | 1),
                                __shfl(bscal, lb | 2), __shfl(bscal, lb | 3));
        }
        float4 bbj;
        {
            int lb = j << 2;
            bbj = make_float4(__shfl(bscal, lb | 0), __shfl(bscal, lb | 1),
                              __shfl(bscal, lb | 2), __shfl(bscal, lb | 3));
        }

        // ---- s3: A = F - B*H, AP = TF - B*HP (ph local) -> LDS ----
        float4 ph4 = make_float4(ph[0], ph[1], ph[2], ph[3]);
#pragma unroll
        for (int r = 0; r < 4; ++r) {
            int i = q + 4*r;
            float av = ((const float*)&zFijv)[r] - dot4(bq[r], zHcjv);
            float ap = tf[r] - dot4(bq[r], ph4);
            sA[i*20 + j]  = av;
            sAP[i*20 + j] = ap;
        }
        __syncthreads();

        // ---- s4: P' = AP A^T + B (R B_j) + Q; fused filter; write P ----
        float4 zA[4];
#pragma unroll
        for (int f = 0; f < 4; ++f) zA[f] = sA4[j*5 + f];   // A row j
        float4 rbtv = make_float4(dot4(zR4[0], bbj), dot4(zR4[1], bbj),
                                  dot4(zR4[2], bbj), dot4(zR4[3], bbj));
#pragma unroll
        for (int r = 0; r < 4; ++r) {
            int i = q + 4*r;
            float acc = zQ[r] + dot4(bq[r], rbtv);
#pragma unroll
            for (int f = 0; f < 4; ++f) acc += dot4(sAP4[i*5 + f], zA[f]);
            sP[i*20 + j] = acc;
        }
        // filter: out[t] = H z_t ; z <- A_t z + B_t obs_t  (lane (g=q, i=j))
        {
            float arr[16] = {zA[0].x,zA[0].y,zA[0].z,zA[0].w,
                             zA[1].x,zA[1].y,zA[1].z,zA[1].w,
                             zA[2].x,zA[2].y,zA[2].z,zA[2].w,
                             zA[3].x,zA[3].y,zA[3].z,zA[3].w};
            float4 oo = sObs4[q*256 + t];
            float o = 0.f, zn = dot4(bbj, oo);
#pragma unroll
            for (int k = 0; k < 16; ++k) {
                float zk = __shfl(zr, gbase + k);
                o  = fmaf(hr[k],  zk, o);
                zn = fmaf(arr[k], zk, zn);
            }
            if (j < 4) sOut[(q*256 + t)*4 + j] = o;
            zr = zn;
        }
        __syncthreads();
    }

    // ---- final output: out[255] = H z_255 ----
    {
        float o = 0.f;
#pragma unroll
        for (int k = 0; k < 16; ++k) {
            float zk = __shfl(zr, gbase + k);
            o = fmaf(hr[k], zk, o);
        }
        if (j < 4) sOut[(q*256 + 255)*4 + j] = o;
    }
    __syncthreads();
    // ---- flush out: 4 batches x 256 steps, coalesced float4 runs ----
    float4* out4 = (float4*)out;
    for (int u = tid; u < 1024; u += 64)
        out4[(blockIdx.x * 4 + (u >> 8)) * NT + (u & 255)] = sOut4[u];
}

extern "C" void kernel_launch(void* const* d_in, const int* in_sizes, int n_in,
                              void* d_out, int out_size, void* d_ws, size_t ws_size,
                              hipStream_t stream) {
    const float* obs = (const float*)d_in[0];   // [B,T,M]
    const float* F   = (const float*)d_in[1];   // [S,S]
    const float* H   = (const float*)d_in[2];   // [M,S]
    const float* Q   = (const float*)d_in[3];   // [S,S]
    const float* R   = (const float*)d_in[4];   // [M,M]
    const float* x0  = (const float*)d_in[5];   // [S]
    const float* sd  = (const float*)d_in[6];   // [S]
    float* out = (float*)d_out;

    hipLaunchKernelGGL(kf_block_kernel, dim3(256), dim3(64), 0, stream,
                       obs, F, H, Q, R, x0, sd, out);
}

// Round 11
// 411.733 us; speedup vs baseline: 1.2337x; 1.2337x over previous
//
#include <hip/hip_runtime.h>

// B=1024 groups, T=256 steps, S=16 states, M=4 measurements
#define NT 256
#define NSTEP 255
#define ELOFF 81664                    // element t at ELOFF + (t-1)*768, t=1..254
#define NEED_WS_BYTES 1110000UL

__device__ __forceinline__ float dot4(float4 a, float4 b) {
    return a.x*b.x + a.y*b.y + a.z*b.z + a.w*b.w;
}

// ---------------- 16x16 matmul helpers (lane (q,j) owns rows q+4r, col j) ----
__device__ __forceinline__ void mm_nn(const float* A, const float* B,
                                      const float* E, float* D, int q, int j) {
    float bc[16];
#pragma unroll
    for (int k = 0; k < 16; ++k) bc[k] = B[k*16 + j];
    float4 b0 = make_float4(bc[0],bc[1],bc[2],bc[3]);
    float4 b1 = make_float4(bc[4],bc[5],bc[6],bc[7]);
    float4 b2 = make_float4(bc[8],bc[9],bc[10],bc[11]);
    float4 b3 = make_float4(bc[12],bc[13],bc[14],bc[15]);
#pragma unroll
    for (int r = 0; r < 4; ++r) {
        int i = q + 4*r;
        const float4* Ar = (const float4*)(A + i*16);
        float acc = E ? E[i*16 + j] : 0.f;
        acc += dot4(Ar[0], b0) + dot4(Ar[1], b1) + dot4(Ar[2], b2) + dot4(Ar[3], b3);
        D[i*16 + j] = acc;
    }
}
__device__ __forceinline__ void mm_nt(const float* A, const float* B,
                                      const float* E, float* D, int q, int j) {
    const float4* Bj = (const float4*)(B + j*16);
    float4 c0 = Bj[0], c1 = Bj[1], c2 = Bj[2], c3 = Bj[3];
#pragma unroll
    for (int r = 0; r < 4; ++r) {
        int i = q + 4*r;
        const float4* Ar = (const float4*)(A + i*16);
        float acc = E ? E[i*16 + j] : 0.f;
        acc += dot4(Ar[0], c0) + dot4(Ar[1], c1) + dot4(Ar[2], c2) + dot4(Ar[3], c3);
        D[i*16 + j] = acc;
    }
}
__device__ __forceinline__ void mm_tn(const float* A, const float* B,
                                      const float* E, float* D, int q, int j) {
    float bc[16];
#pragma unroll
    for (int k = 0; k < 16; ++k) bc[k] = B[k*16 + j];
#pragma unroll
    for (int r = 0; r < 4; ++r) {
        int i = q + 4*r;
        float acc = E ? E[i*16 + j] : 0.f;
#pragma unroll
        for (int k = 0; k < 16; ++k) acc += A[k*16 + i] * bc[k];
        D[i*16 + j] = acc;
    }
}

// ---------------- Gauss-Jordan invert 16x16 (W: 16x32 augmented, stride 36) --
// Caller fills W left half (cols 0..15) and barriers; result -> X (stride 16).
__device__ void gj_invert16(float* W, float* X, int tid) {
    int row = tid >> 2, cq = tid & 3;
#pragma unroll
    for (int c = 0; c < 4; ++c) {
        int cc = cq*4 + c;
        W[row*36 + 16 + cc] = (row == cc) ? 1.f : 0.f;
    }
    __syncthreads();
    for (int p = 0; p < 16; ++p) {
        float pinv = 1.f / W[p*36 + p];
        if (row == p) {
#pragma unroll
            for (int c = 0; c < 8; ++c) W[p*36 + cq*8 + c] *= pinv;
        }
        __syncthreads();
        float fac = W[row*36 + p];
        if (row != p) {
#pragma unroll
            for (int c = 0; c < 8; ++c) {
                int cc = cq*8 + c;
                W[row*36 + cc] -= fac * W[p*36 + cc];
            }
        }
        __syncthreads();
    }
    int q = tid >> 4, j = tid & 15;
#pragma unroll
    for (int r = 0; r < 4; ++r) {
        int i = q + 4*r;
        X[i*16 + j] = W[i*36 + 16 + j];
    }
}

// ---------------- element combine: (A12,C12,J12) = E2 ∘ E1 (E1 first) -------
// A12 = A2 X A1 ; C12 = A2 X C1 A2^T + C2 ; J12 = A1^T J2 X A1 + J1,
// X = (I + C1 J2)^{-1}.  Caller barriers before (inputs staged).
__device__ void el_combine(const float* A1, const float* C1, const float* J1,
                           const float* A2, const float* C2, const float* J2,
                           float* OA, float* OC, float* OJ,
                           float* W, float* T1, float* T2, float* T3, int tid) {
    int q = tid >> 4, j = tid & 15;
    {   // W left = I + C1*J2
        float bc[16];
#pragma unroll
        for (int k = 0; k < 16; ++k) bc[k] = J2[k*16 + j];
        float4 b0 = make_float4(bc[0],bc[1],bc[2],bc[3]);
        float4 b1 = make_float4(bc[4],bc[5],bc[6],bc[7]);
        float4 b2 = make_float4(bc[8],bc[9],bc[10],bc[11]);
        float4 b3 = make_float4(bc[12],bc[13],bc[14],bc[15]);
#pragma unroll
        for (int r = 0; r < 4; ++r) {
            int i = q + 4*r;
            const float4* Cr = (const float4*)(C1 + i*16);
            float acc = (i == j) ? 1.f : 0.f;
            acc += dot4(Cr[0], b0) + dot4(Cr[1], b1) + dot4(Cr[2], b2) + dot4(Cr[3], b3);
            W[i*36 + j] = acc;
        }
    }
    __syncthreads();
    gj_invert16(W, T1, tid);            // X -> T1
    __syncthreads();
    mm_nn(A2, T1, nullptr, T2, q, j);   // T = A2*X
    __syncthreads();
    mm_nn(T2, A1, nullptr, OA, q, j);   // A12
    mm_nn(T2, C1, nullptr, T3, q, j);   // U = T*C1
    __syncthreads();
    mm_nt(T3, A2, C2, OC, q, j);        // C12 = U*A2^T + C2
    mm_nn(J2, T1, nullptr, T2, q, j);   // W5 = J2*X
    __syncthreads();
    mm_tn(A1, T2, nullptr, T3, q, j);   // Y = A1^T*W5
    __syncthreads();
    mm_nn(T3, A1, J1, OJ, q, j);        // J12 = Y*A1 + J1
    __syncthreads();
}

// ---------------- L1: E^1 = (F, Q, H^T R^-1 H); serial E^2..E^8 -------------
__global__ __launch_bounds__(64) void scan_init_kernel(
    const float* __restrict__ Fg, const float* __restrict__ Hg,
    const float* __restrict__ Qg, const float* __restrict__ Rg,
    float* __restrict__ ws)
{
    __shared__ float4 b1[64*3], b2[64*3], bo[64*3], bt[64*3], bw[144];
    __shared__ float  sH[64], sRinv[16], sT4[64];
    float* eA1 = (float*)b1;        float* eC1 = eA1 + 256;  float* eJ1 = eA1 + 512;
    float* eA2 = (float*)b2;        float* eC2 = eA2 + 256;  float* eJ2 = eA2 + 512;
    float* OA  = (float*)bo;        float* OC  = OA + 256;   float* OJ  = OA + 512;
    float* T1  = (float*)bt;        float* T2  = T1 + 256;   float* T3  = T1 + 512;
    float* W   = (float*)bw;

    const int tid = threadIdx.x;
    const int q = tid >> 4, j = tid & 15;

    for (int u = tid; u < 256; u += 64) { eA2[u] = Fg[u]; eC2[u] = Qg[u]; }
    sH[tid] = Hg[tid];
    if (tid < 16) {     // Rinv via 4x4 cofactors (proven pattern)
        int rr = tid >> 2, cc_ = tid & 3;
        int ra = (rr == 0) ? 1 : 0, rb = (rr <= 1) ? 2 : 1, rc = (rr <= 2) ? 3 : 2;
        const float4* Rg4 = (const float4*)Rg;
        float4 a = Rg4[ra], b = Rg4[rb], c = Rg4[rc], sm = Rg4[rr];
        float M0 = a.y*(b.z*c.w - b.w*c.z) - a.z*(b.y*c.w - b.w*c.y) + a.w*(b.y*c.z - b.z*c.y);
        float M1 = a.x*(b.z*c.w - b.w*c.z) - a.z*(b.x*c.w - b.w*c.x) + a.w*(b.x*c.z - b.z*c.x);
        float M2 = a.x*(b.y*c.w - b.w*c.y) - a.y*(b.x*c.w - b.w*c.x) + a.w*(b.x*c.y - b.y*c.x);
        float M3 = a.x*(b.y*c.z - b.z*c.y) - a.y*(b.x*c.z - b.z*c.x) + a.z*(b.x*c.y - b.y*c.x);
        float sg = (rr & 1) ? -1.f : 1.f;
        float c0 = sg*M0, c1 = -sg*M1, c2 = sg*M2, c3 = -sg*M3;
        float det = sm.x*c0 + sm.y*c1 + sm.z*c2 + sm.w*c3;
        float cofc = (cc_ == 0) ? c0 : ((cc_ == 1) ? c1 : ((cc_ == 2) ? c2 : c3));
        sRinv[cc_*4 + rr] = cofc / det;
    }
    __syncthreads();
    {   // T4 = Rinv * H  (4x16)
        int m = tid >> 4, j2 = tid & 15;
        float acc = 0.f;
#pragma unroll
        for (int n = 0; n < 4; ++n) acc += sRinv[m*4 + n] * sH[n*16 + j2];
        sT4[m*16 + j2] = acc;
    }
    __syncthreads();
#pragma unroll
    for (int r = 0; r < 4; ++r) {   // J = H^T * T4
        int i = q + 4*r;
        float acc = 0.f;
#pragma unroll
        for (int m = 0; m < 4; ++m) acc += sH[m*16 + i] * sT4[m*16 + j];
        eJ2[i*16 + j] = acc;
    }
    __syncthreads();
    // store E^1; slot1 = E^1
    for (int u = tid; u < 256; u += 64) {
        ws[ELOFF + u]       = eA2[u];
        ws[ELOFF + 256 + u] = eC2[u];
        ws[ELOFF + 512 + u] = eJ2[u];
        eA1[u] = eA2[u]; eC1[u] = eC2[u]; eJ1[u] = eJ2[u];
    }
    __syncthreads();
    for (int k = 2; k <= 8; ++k) {
        el_combine(eA1, eC1, eJ1, eA2, eC2, eJ2, OA, OC, OJ, W, T1, T2, T3, tid);
        int base = ELOFF + (k - 1)*768;
        for (int u = tid; u < 256; u += 64) {
            ws[base + u]       = OA[u];
            ws[base + 256 + u] = OC[u];
            ws[base + 512 + u] = OJ[u];
            eA1[u] = OA[u]; eC1[u] = OC[u]; eJ1[u] = OJ[u];
        }
        __syncthreads();
    }
}

// ---------------- Lk: E^{dstBase+b} = E^{hi} ∘ E^{1+b} ----------------------
__global__ __launch_bounds__(64) void scan_power_kernel(
    float* __restrict__ ws, int hi, int dstBase)
{
    __shared__ float4 b1[64*3], b2[64*3], bo[64*3], bt[64*3], bw[144];
    float* eA1 = (float*)b1;  float* eC1 = eA1 + 256;  float* eJ1 = eA1 + 512;
    float* eA2 = (float*)b2;  float* eC2 = eA2 + 256;  float* eJ2 = eA2 + 512;
    float* OA  = (float*)bo;  float* OC  = OA + 256;   float* OJ  = OA + 512;
    float* T1  = (float*)bt;  float* T2  = T1 + 256;   float* T3  = T1 + 512;
    float* W   = (float*)bw;

    const int tid = threadIdx.x;
    const int lo = 1 + blockIdx.x;
    const int loB = ELOFF + (lo - 1)*768, hiB = ELOFF + (hi - 1)*768;
    for (int u = tid; u < 256; u += 64) {
        eA1[u] = ws[loB + u];  eC1[u] = ws[loB + 256 + u];  eJ1[u] = ws[loB + 512 + u];
        eA2[u] = ws[hiB + u];  eC2[u] = ws[hiB + 256 + u];  eJ2[u] = ws[hiB + 512 + u];
    }
    __syncthreads();
    el_combine(eA1, eC1, eJ1, eA2, eC2, eJ2, OA, OC, OJ, W, T1, T2, T3, tid);
    int dB = ELOFF + (dstBase + (int)blockIdx.x - 1)*768;
    for (int u = tid; u < 256; u += 64) {
        ws[dB + u] = OA[u]; ws[dB + 256 + u] = OC[u]; ws[dB + 512 + u] = OJ[u];
    }
}

// ---------------- per-t gains: P_t = E^t(P0) -> S,B,A_cl -> ws[t*320] -------
__global__ __launch_bounds__(64) void scan_gain_kernel(
    const float* __restrict__ Fg, const float* __restrict__ Hg,
    const float* __restrict__ Qg, const float* __restrict__ Rg,
    const float* __restrict__ sdg, float* __restrict__ ws)
{
    __shared__ float4 bF[64], bP0[64], bE[64*3], bt[64*3], bw[144];
    __shared__ float  sH[64], sHP[64], sS[16];
    __shared__ float4 sV4[16], sB4[16];
    float* sF  = (float*)bF;
    float* sP0 = (float*)bP0;
    float* eA = (float*)bE;  float* eC = eA + 256;  float* eJ = eA + 512;
    float* T1 = (float*)bt;  float* T2 = T1 + 256;  float* T3 = T1 + 512;
    float* W  = (float*)bw;
    float* sV = (float*)sV4; float* sB = (float*)sB4;
    float4* sS4 = (float4*)sS;

    const int tid = threadIdx.x;
    const int q = tid >> 4, j = tid & 15;
    const int bi = tid >> 2, bm = tid & 3;
    const int t = blockIdx.x;

    for (int u = tid; u < 256; u += 64) sF[u] = Fg[u];
    sH[tid] = Hg[tid];
    if (t > 0) {
        int base = ELOFF + (t - 1)*768;
        for (int u = tid; u < 256; u += 64) {
            eA[u] = ws[base + u]; eC[u] = ws[base + 256 + u]; eJ[u] = ws[base + 512 + u];
        }
    }
    float sd2[16];
    {
        const float4* sd4 = (const float4*)sdg;
#pragma unroll
        for (int f = 0; f < 4; ++f) {
            float4 s = sd4[f];
            sd2[f*4+0] = s.x*s.x; sd2[f*4+1] = s.y*s.y;
            sd2[f*4+2] = s.z*s.z; sd2[f*4+3] = s.w*s.w;
        }
    }
    __syncthreads();
    // P0 = F diag(sd^2) F^T + Q
#pragma unroll
    for (int r = 0; r < 4; ++r) {
        int i = q + 4*r;
        float acc = Qg[i*16 + j];
#pragma unroll
        for (int k = 0; k < 16; ++k) acc += sF[i*16 + k] * sd2[k] * sF[j*16 + k];
        sP0[i*16 + j] = acc;
    }
    __syncthreads();

    if (t == 0) {
#pragma unroll
        for (int r = 0; r < 4; ++r) { int i = q + 4*r; T2[i*16 + j] = sP0[i*16 + j]; }
        __syncthreads();
    } else {
        {   // W left = I + P0*J
            float bc[16];
#pragma unroll
            for (int k = 0; k < 16; ++k) bc[k] = eJ[k*16 + j];
            float4 b0 = make_float4(bc[0],bc[1],bc[2],bc[3]);
            float4 b1 = make_float4(bc[4],bc[5],bc[6],bc[7]);
            float4 b2 = make_float4(bc[8],bc[9],bc[10],bc[11]);
            float4 b3 = make_float4(bc[12],bc[13],bc[14],bc[15]);
#pragma unroll
            for (int r = 0; r < 4; ++r) {
                int i = q + 4*r;
                const float4* Pr = (const float4*)(sP0 + i*16);
                float acc = (i == j) ? 1.f : 0.f;
                acc += dot4(Pr[0],b0) + dot4(Pr[1],b1) + dot4(Pr[2],b2) + dot4(Pr[3],b3);
                W[i*36 + j] = acc;
            }
        }
        __syncthreads();
        gj_invert16(W, T1, tid);            // X
        __syncthreads();
        mm_nn(T1, sP0, nullptr, T2, q, j);  // G = X*P0
        __syncthreads();
#pragma unroll
        for (int r = 0; r < 4; ++r) {       // symmetrize G -> T3
            int i = q + 4*r;
            T3[i*16 + j] = 0.5f*(T2[i*16 + j] + T2[j*16 + i]);
        }
        __syncthreads();
        mm_nn(eA, T3, nullptr, T1, q, j);   // U = A*G
        __syncthreads();
        mm_nt(T1, eA, eC, T2, q, j);        // P_t = U*A^T + C
        __syncthreads();
    }

    // gains from P (T2): TF = F*P -> T1 ; HP = H*P
    mm_nn(sF, T2, nullptr, T1, q, j);
    {
        int m = tid >> 4, s = tid & 15;
        float acc = 0.f;
#pragma unroll
        for (int k = 0; k < 16; ++k) acc += sH[m*16 + k] * T2[k*16 + s];
        sHP[m*16 + s] = acc;
    }
    __syncthreads();
    // V = TF*H^T ; S = HP*H^T + R
    {
        const float4* TFr = (const float4*)(T1 + bi*16);
        const float4* Hm  = (const float4*)(sH + bm*16);
        float acc = 0.f;
#pragma unroll
        for (int f = 0; f < 4; ++f) acc += dot4(TFr[f], Hm[f]);
        sV[bi*4 + bm] = acc;
    }
    if (tid < 16) {
        int m = tid >> 2, n = tid & 3;
        const float4* HPm = (const float4*)(sHP + m*16);
        const float4* Hn  = (const float4*)(sH + n*16);
        float acc = Rg[m*4 + n];
#pragma unroll
        for (int f = 0; f < 4; ++f) acc += dot4(HPm[f], Hn[f]);
        sS[m*4 + n] = acc;
    }
    __syncthreads();
    // B = V*S^{-1} via cofactors (proven R5 pattern)
    {
        int ra = (bm == 0) ? 1 : 0;
        int rb = (bm <= 1) ? 2 : 1;
        int rc = (bm <= 2) ? 3 : 2;
        float4 a = sS4[ra], b = sS4[rb], c = sS4[rc], sm = sS4[bm];
        float M0 = a.y*(b.z*c.w - b.w*c.z) - a.z*(b.y*c.w - b.w*c.y) + a.w*(b.y*c.z - b.z*c.y);
        float M1 = a.x*(b.z*c.w - b.w*c.z) - a.z*(b.x*c.w - b.w*c.x) + a.w*(b.x*c.z - b.z*c.x);
        float M2 = a.x*(b.y*c.w - b.w*c.y) - a.y*(b.x*c.w - b.w*c.x) + a.w*(b.x*c.y - b.y*c.x);
        float M3 = a.x*(b.y*c.z - b.z*c.y) - a.y*(b.x*c.z - b.z*c.x) + a.z*(b.x*c.y - b.y*c.x);
        float sg = (bm & 1) ? -1.f : 1.f;
        float c0 = sg*M0, c1 = -sg*M1, c2 = sg*M2, c3 = -sg*M3;
        float det = sm.x*c0 + sm.y*c1 + sm.z*c2 + sm.w*c3;
        float4 vv = sV4[bi];
        sB[tid] = (vv.x*c0 + vv.y*c1 + vv.z*c2 + vv.w*c3) / det;
    }
    __syncthreads();
    // A_cl = F - B*H (row-major) + B -> ws[t*320]
    {
        float h0 = sH[j], h1 = sH[16 + j], h2 = sH[32 + j], h3 = sH[48 + j];
#pragma unroll
        for (int r = 0; r < 4; ++r) {
            int i = q + 4*r;
            float4 bb = sB4[i];
            ws[t*320 + i*16 + j] = sF[i*16 + j] - (bb.x*h0 + bb.y*h1 + bb.z*h2 + bb.w*h3);
        }
        ws[t*320 + 256 + tid] = sB[tid];
    }
}

// ---------------- filter: 256 blocks x 64, 4 batches, z in regs -------------
__global__ __launch_bounds__(64) void scan_filter_kernel(
    const float* __restrict__ obs, const float* __restrict__ Fg,
    const float* __restrict__ Hg,  const float* __restrict__ x0g,
    const float* __restrict__ ws,  float* __restrict__ out)
{
    __shared__ float4 sA4[16 * 80];   // [ss][row][20] = 20 KB
    __shared__ float4 sB4v[16 * 16];
    __shared__ float4 sObs4[4 * 16];  // [g][ss]
    __shared__ float4 sOut4[16 * 4];  // [ss][g]
    float* sA   = (float*)sA4;
    float* sOut = (float*)sOut4;

    const int tid = threadIdx.x;
    const int g = tid >> 4, i = tid & 15;
    const int gbase = tid & 48;
    const int b = blockIdx.x * 4 + g;

    const float4* Hg4 = (const float4*)Hg;
    float4 h0 = Hg4[(i & 3)*4 + 0], h1 = Hg4[(i & 3)*4 + 1],
           h2 = Hg4[(i & 3)*4 + 2], h3 = Hg4[(i & 3)*4 + 3];
    float hr[16] = {h0.x,h0.y,h0.z,h0.w, h1.x,h1.y,h1.z,h1.w,
                    h2.x,h2.y,h2.z,h2.w, h3.x,h3.y,h3.z,h3.w};

    // z0 = F x0
    float zr;
    {
        const float4* Fg4 = (const float4*)Fg;
        const float4* x04 = (const float4*)x0g;
        float acc = 0.f;
#pragma unroll
        for (int f = 0; f < 4; ++f) acc += dot4(Fg4[i*4 + f], x04[f]);
        zr = acc;
    }

    const float4* wsf4 = (const float4*)ws;
    const float4* obs4 = (const float4*)obs;
    float4* out4 = (float4*)out;

    for (int chunk = 0; chunk < NSTEP; chunk += 16) {
        int len = NSTEP - chunk; if (len > 16) len = 16;
        __syncthreads();
        for (int u = tid; u < len * 64; u += 64) {
            int ss = u >> 6, rem = u & 63, row = rem >> 2, f = rem & 3;
            sA4[ss*80 + row*5 + f] = wsf4[(chunk + ss)*80 + rem];
        }
        for (int u = tid; u < len * 16; u += 64) {
            int ss = u >> 4, r2 = u & 15;
            sB4v[ss*16 + r2] = wsf4[(chunk + ss)*80 + 64 + r2];
        }
        {   // 64 (gg,ss) slots, one per lane
            int ss = tid & 15, gg = tid >> 4;
            if (ss < len)
                sObs4[gg*16 + ss] = obs4[(blockIdx.x*4 + gg) * NT + chunk + ss];
        }
        __syncthreads();
        for (int ss = 0; ss < len; ++ss) {
            const float4* Ar = (const float4*)(sA + ss*320 + i*20);
            float4 a0 = Ar[0], a1 = Ar[1], a2 = Ar[2], a3 = Ar[3];
            float ar[16] = {a0.x,a0.y,a0.z,a0.w, a1.x,a1.y,a1.z,a1.w,
                            a2.x,a2.y,a2.z,a2.w, a3.x,a3.y,a3.z,a3.w};
            float4 bb = sB4v[ss*16 + i];
            float4 oo = sObs4[g*16 + ss];
            float o = 0.f, zn = dot4(bb, oo);
#pragma unroll
            for (int k = 0; k < 16; ++k) {
                float zk = __shfl(zr, gbase + k);
                o  = fmaf(hr[k], zk, o);     // out time t = chunk+ss (H z_t)
                zn = fmaf(ar[k], zk, zn);
            }
            if (i < 4) sOut[ss*16 + g*4 + i] = o;
            zr = zn;
        }
        __syncthreads();
        if (i < len) out4[b * NT + chunk + i] = sOut4[i*4 + g];
    }
    // final: out[255] = H z_255
    {
        float o = 0.f;
#pragma unroll
        for (int k = 0; k < 16; ++k) {
            float zk = __shfl(zr, gbase + k);
            o = fmaf(hr[k], zk, o);
        }
        if (i < 4) out[(b * NT + 255)*4 + i] = o;
    }
}

// ================= FALLBACK: proven R9 fused kernel (242 us) =================
__global__ __launch_bounds__(64) void kf_block_kernel(
    const float* __restrict__ obs, const float* __restrict__ Fg,
    const float* __restrict__ Hg,  const float* __restrict__ Qg,
    const float* __restrict__ Rg,  const float* __restrict__ x0g,
    const float* __restrict__ sdg, float* __restrict__ out)
{
    __shared__ float4 sF4[80], sP4[80], sA4[80], sAP4[80];
    __shared__ float4 sHP4[16], sV4[16], sB4[16], sS4[4];
    __shared__ float  sH[64], sZ[16];
    __shared__ float4 sObs4[1024], sOut4v[1024];

    float* sF  = (float*)sF4;   float* sP  = (float*)sP4;
    float* sA  = (float*)sA4;   float* sAP = (float*)sAP4;
    float* sHP = (float*)sHP4;  float* sV  = (float*)sV4;
    float* sB  = (float*)sB4;   float* sS  = (float*)sS4;
    float* sOut = (float*)sOut4v;

    const int tid = threadIdx.x;
    const int q  = tid >> 4, j = tid & 15;
    const int bi = tid >> 2, bm = tid & 3;
    const int gbase = tid & 48;

    const float4* Fg4 = (const float4*)Fg;
    const float4* Hg4 = (const float4*)Hg;
    const float4* Rg4 = (const float4*)Rg;
    const float4* obs4g = (const float4*)obs;

    for (int u = tid; u < 256; u += 64) sF[(u >> 4) * 20 + (u & 15)] = Fg[u];
    sH[tid] = Hg[tid];
    for (int u = tid; u < 1024; u += 64)
        sObs4[u] = obs4g[(blockIdx.x * 4 + (u >> 8)) * NT + (u & 255)];

    float4 zF[4][4], zFbi[4], zFj[4], zHq[4], zHn[4], zHrow4[4];
#pragma unroll
    for (int r = 0; r < 4; ++r)
#pragma unroll
        for (int f = 0; f < 4; ++f) zF[r][f] = Fg4[(q + 4*r)*4 + f];
#pragma unroll
    for (int f = 0; f < 4; ++f) {
        zFbi[f]   = Fg4[bi*4 + f];
        zFj[f]    = Fg4[j*4 + f];
        zHq[f]    = Hg4[q*4 + f];
        zHn[f]    = Hg4[bm*4 + f];
        zHrow4[f] = Hg4[(j & 3)*4 + f];
    }
    float hr[16] = {zHrow4[0].x,zHrow4[0].y,zHrow4[0].z,zHrow4[0].w,
                    zHrow4[1].x,zHrow4[1].y,zHrow4[1].z,zHrow4[1].w,
                    zHrow4[2].x,zHrow4[2].y,zHrow4[2].z,zHrow4[2].w,
                    zHrow4[3].x,zHrow4[3].y,zHrow4[3].z,zHrow4[3].w};
    float zQ[4];
#pragma unroll
    for (int r = 0; r < 4; ++r) zQ[r] = Qg[(q + 4*r)*16 + j];
    float  zRs = Rg[tid & 15];
    float4 zR4[4];
#pragma unroll
    for (int m = 0; m < 4; ++m) zR4[m] = Rg4[m];
    float4 zHcjv = make_float4(Hg[j], Hg[16 + j], Hg[32 + j], Hg[48 + j]);
    float4 zFijv = make_float4(Fg[q*16 + j],     Fg[(q+4)*16 + j],
                               Fg[(q+8)*16 + j], Fg[(q+12)*16 + j]);
    float4 zSd2[4];
#pragma unroll
    for (int f = 0; f < 4; ++f) {
        float4 s = ((const float4*)sdg)[f];
        zSd2[f] = make_float4(s.x*s.x, s.y*s.y, s.z*s.z, s.w*s.w);
    }
    __syncthreads();

#pragma unroll
    for (int r = 0; r < 4; ++r) {
        float acc = zQ[r];
#pragma unroll
        for (int f = 0; f < 4; ++f) {
            float4 a = zF[r][f], b = zFj[f], s = zSd2[f];
            acc += a.x*s.x*b.x + a.y*s.y*b.y + a.z*s.z*b.z + a.w*s.w*b.w;
        }
        sP[(q + 4*r)*20 + j] = acc;
    }
    if (tid < 16) {
        float acc = 0.f;
#pragma unroll
        for (int f = 0; f < 4; ++f) {
            float4 fr = ((float4*)(sF + tid*20))[f];
            float4 xv = ((const float4*)x0g)[f];
            acc += dot4(fr, xv);
        }
        sZ[tid] = acc;
    }
    __syncthreads();
    float zr = sZ[j];

    for (int t = 0; t < NSTEP; ++t) {
        float4 zP[4];
#pragma unroll
        for (int f = 0; f < 4; ++f) zP[f] = sP4[j*5 + f];
        float tf[4], hp = 0.f;
#pragma unroll
        for (int r = 0; r < 4; ++r) {
            float acc = 0.f;
#pragma unroll
            for (int f = 0; f < 4; ++f) acc += dot4(zF[r][f], zP[f]);
            tf[r] = acc;
        }
#pragma unroll
        for (int f = 0; f < 4; ++f) hp += dot4(zHq[f], zP[f]);
        sHP[q*16 + j] = hp;
        __syncthreads();
        {
            float acc = 0.f;
#pragma unroll
            for (int f = 0; f < 4; ++f) acc += dot4(zFbi[f], sHP4[bm*4 + f]);
            sV[bi*4 + bm] = acc;
        }
        if (tid < 16) {
            float acc = zRs;
#pragma unroll
            for (int f = 0; f < 4; ++f) acc += dot4(sHP4[(tid >> 2)*4 + f], zHn[f]);
            sS[tid] = acc;
        }
        __syncthreads();
        {
            int ra = (bm == 0) ? 1 : 0;
            int rb = (bm <= 1) ? 2 : 1;
            int rc = (bm <= 2) ? 3 : 2;
            float4 a = sS4[ra], b = sS4[rb], c = sS4[rc], sm = sS4[bm];
            float M0 = a.y*(b.z*c.w - b.w*c.z) - a.z*(b.y*c.w - b.w*c.y) + a.w*(b.y*c.z - b.z*c.y);
            float M1 = a.x*(b.z*c.w - b.w*c.z) - a.z*(b.x*c.w - b.w*c.x) + a.w*(b.x*c.z - b.z*c.x);
            float M2 = a.x*(b.y*c.w - b.w*c.y) - a.y*(b.x*c.w - b.w*c.x) + a.w*(b.x*c.y - b.y*c.x);
            float M3 = a.x*(b.y*c.z - b.z*c.y) - a.y*(b.x*c.z - b.z*c.x) + a.z*(b.x*c.y - b.y*c.x);
            float sg = (bm & 1) ? -1.f : 1.f;
            float c0 = sg*M0, c1 = -sg*M1, c2 = sg*M2, c3 = -sg*M3;
            float det = sm.x*c0 + sm.y*c1 + sm.z*c2 + sm.w*c3;
            float4 vv = sV4[bi];
            sB[tid] = (vv.x*c0 + vv.y*c1 + vv.z*c2 + vv.w*c3) / det;
        }
        __syncthreads();
        float4 bq[4], rbtv;
        {
            float4 hpcv = make_float4(sHP[j], sHP[16 + j], sHP[32 + j], sHP[48 + j]);
            float4 bj = sB4[j];
#pragma unroll
            for (int r = 0; r < 4; ++r) {
                int i = q + 4*r;
                bq[r] = sB4[i];
                sA[i*20 + j]  = ((const float*)&zFijv)[r] - dot4(bq[r], zHcjv);
                sAP[i*20 + j] = tf[r] - dot4(bq[r], hpcv);
            }
            rbtv = make_float4(dot4(zR4[0], bj), dot4(zR4[1], bj),
                               dot4(zR4[2], bj), dot4(zR4[3], bj));
        }
        __syncthreads();
        float4 zA[4];
#pragma unroll
        for (int f = 0; f < 4; ++f) zA[f] = sA4[j*5 + f];
#pragma unroll
        for (int r = 0; r < 4; ++r) {
            int i = q + 4*r;
            float acc = zQ[r] + dot4(bq[r], rbtv);
#pragma unroll
            for (int f = 0; f < 4; ++f) acc += dot4(sAP4[i*5 + f], zA[f]);
            sP[i*20 + j] = acc;
        }
        {
            float arr[16] = {zA[0].x,zA[0].y,zA[0].z,zA[0].w,
                             zA[1].x,zA[1].y,zA[1].z,zA[1].w,
                             zA[2].x,zA[2].y,zA[2].z,zA[2].w,
                             zA[3].x,zA[3].y,zA[3].z,zA[3].w};
            float4 bb = sB4[j];
            float4 oo = sObs4[q*256 + t];
            float o = 0.f, zn = dot4(bb, oo);
#pragma unroll
            for (int k = 0; k < 16; ++k) {
                float zk = __shfl(zr, gbase + k);
                o  = fmaf(hr[k],  zk, o);
                zn = fmaf(arr[k], zk, zn);
            }
            if (j < 4) sOut[(q*256 + t)*4 + j] = o;
            zr = zn;
        }
        __syncthreads();
    }
    {
        float o = 0.f;
#pragma unroll
        for (int k = 0; k < 16; ++k) {
            float zk = __shfl(zr, gbase + k);
            o = fmaf(hr[k], zk, o);
        }
        if (j < 4) sOut[(q*256 + 255)*4 + j] = o;
    }
    __syncthreads();
    float4* out4 = (float4*)out;
    for (int u = tid; u < 1024; u += 64)
        out4[(blockIdx.x * 4 + (u >> 8)) * NT + (u & 255)] = sOut4v[u];
}

extern "C" void kernel_launch(void* const* d_in, const int* in_sizes, int n_in,
                              void* d_out, int out_size, void* d_ws, size_t ws_size,
                              hipStream_t stream) {
    const float* obs = (const float*)d_in[0];   // [B,T,M]
    const float* F   = (const float*)d_in[1];   // [S,S]
    const float* H   = (const float*)d_in[2];   // [M,S]
    const float* Q   = (const float*)d_in[3];   // [S,S]
    const float* R   = (const float*)d_in[4];   // [M,M]
    const float* x0  = (const float*)d_in[5];   // [S]
    const float* sd  = (const float*)d_in[6];   // [S]
    float* ws  = (float*)d_ws;
    float* out = (float*)d_out;

    if (ws_size < NEED_WS_BYTES) {
        // fallback: proven fused serial kernel (R9)
        hipLaunchKernelGGL(kf_block_kernel, dim3(256), dim3(64), 0, stream,
                           obs, F, H, Q, R, x0, sd, out);
        return;
    }
    // parallel-scan path: powers of the Riccati element by doubling
    hipLaunchKernelGGL(scan_init_kernel,  dim3(1),   dim3(64), 0, stream, F, H, Q, R, ws);
    hipLaunchKernelGGL(scan_power_kernel, dim3(8),   dim3(64), 0, stream, ws, 8,   9);
    hipLaunchKernelGGL(scan_power_kernel, dim3(16),  dim3(64), 0, stream, ws, 16,  17);
    hipLaunchKernelGGL(scan_power_kernel, dim3(32),  dim3(64), 0, stream, ws, 32,  33);
    hipLaunchKernelGGL(scan_power_kernel, dim3(64),  dim3(64), 0, stream, ws, 64,  65);
    hipLaunchKernelGGL(scan_power_kernel, dim3(126), dim3(64), 0, stream, ws, 128, 129);
    hipLaunchKernelGGL(scan_gain_kernel,  dim3(255), dim3(64), 0, stream, F, H, Q, R, sd, ws);
    hipLaunchKernelGGL(scan_filter_kernel,dim3(256), dim3(64), 0, stream, obs, F, H, x0, ws, out);
}